// Round 1
// baseline (305.345 us; speedup 1.0000x reference)
//
#include <hip/hip_runtime.h>

// NeuralRodriguesOperator: B=512, C_L_in=C_L_out=64, C_J=16, 4x4 matrices.
// out[b,j,p,r] = sum_{i,q} F[b,i,p,q]*U[b,j,i,q,r] + Ub[b,j,i,p,q]*F[b,i,q,r]
// U  = W_bias  + sum_c W_cos[...,c,..]*cos(theta[b,c]) + W_sin*sin(...)
// Ub = Wb_bias + sum_c Wb_cos*cos + Wb_sin*sin
//
// Structure: lane = batch b (wave-uniform weight addresses -> s_load broadcast),
// block = (j, b-group of 256, i-split of 32). fp32 VALU throughout.

#define NRO_B   512
#define NRO_CL  64
#define NRO_CJ  16

__global__ __launch_bounds__(256) void nro_main_kernel(
    const float* __restrict__ F_in,     // (B, CL, 4, 4)
    const float* __restrict__ theta,    // (B, CJ)
    const float* __restrict__ W_bias,   // (CL, CL, 4, 4)
    const float* __restrict__ W_cos,    // (CL, CL, CJ, 4, 4)
    const float* __restrict__ W_sin,
    const float* __restrict__ Wb_bias,
    const float* __restrict__ Wb_cos,
    const float* __restrict__ Wb_sin,
    float* __restrict__ out)            // (B, CL, 4, 4), pre-zeroed
{
    const int j  = blockIdx.x;                          // 0..63  (C_L_out)
    const int b  = blockIdx.y * 256 + threadIdx.x;      // 0..511
    const int i0 = blockIdx.z * 32;                     // i-split: 0 or 32

    // Per-lane cos/sin of theta[b, :]
    float csc[NRO_CJ], css[NRO_CJ];
    #pragma unroll
    for (int c = 0; c < NRO_CJ; ++c) {
        float t = theta[b * NRO_CJ + c];
        csc[c] = __cosf(t);
        css[c] = __sinf(t);
    }

    float acc[16];
    #pragma unroll
    for (int e = 0; e < 16; ++e) acc[e] = 0.0f;

    for (int ii = 0; ii < 32; ++ii) {
        const int i  = i0 + ii;
        const int ji = j * NRO_CL + i;

        // Wave-uniform weight slices for this (j, i)
        const float* __restrict__ wb  = W_bias  + ji * 16;
        const float* __restrict__ wbb = Wb_bias + ji * 16;
        const float* __restrict__ wc  = W_cos   + ji * 256;
        const float* __restrict__ wsn = W_sin   + ji * 256;
        const float* __restrict__ wbc = Wb_cos  + ji * 256;
        const float* __restrict__ wbs = Wb_sin  + ji * 256;

        // Per-lane F tile: F[b, i, :, :] (16 contiguous floats)
        float f[16];
        const float4* fp = (const float4*)(F_in + (b * NRO_CL + i) * 16);
        #pragma unroll
        for (int v = 0; v < 4; ++v) {
            float4 x = fp[v];
            f[v * 4 + 0] = x.x; f[v * 4 + 1] = x.y;
            f[v * 4 + 2] = x.z; f[v * 4 + 3] = x.w;
        }

        // Build U, Ub for this (b, j, i): U[x*4+y] = U[b,j,i,x,y]
        float U[16], Ub[16];
        #pragma unroll
        for (int e = 0; e < 16; ++e) { U[e] = wb[e]; Ub[e] = wbb[e]; }

        #pragma unroll 4
        for (int c = 0; c < NRO_CJ; ++c) {
            const float cc = csc[c];
            const float ss = css[c];
            #pragma unroll
            for (int e = 0; e < 16; ++e) {
                U[e]  = fmaf(wc [c * 16 + e], cc, U[e]);
                U[e]  = fmaf(wsn[c * 16 + e], ss, U[e]);
                Ub[e] = fmaf(wbc[c * 16 + e], cc, Ub[e]);
                Ub[e] = fmaf(wbs[c * 16 + e], ss, Ub[e]);
            }
        }

        // acc[p,r] += sum_q F[p,q]*U[q,r] + Ub[p,q]*F[q,r]
        #pragma unroll
        for (int p = 0; p < 4; ++p) {
            #pragma unroll
            for (int r = 0; r < 4; ++r) {
                float a = acc[p * 4 + r];
                #pragma unroll
                for (int q = 0; q < 4; ++q) {
                    a = fmaf(f[p * 4 + q],  U[q * 4 + r], a);
                    a = fmaf(Ub[p * 4 + q], f[q * 4 + r], a);
                }
                acc[p * 4 + r] = a;
            }
        }
    }

    // Epilogue: accumulate the i-split partials into out[b, j, :, :]
    float* o = out + (b * NRO_CL + j) * 16;
    #pragma unroll
    for (int e = 0; e < 16; ++e) atomicAdd(o + e, acc[e]);
}

extern "C" void kernel_launch(void* const* d_in, const int* in_sizes, int n_in,
                              void* d_out, int out_size, void* d_ws, size_t ws_size,
                              hipStream_t stream) {
    const float* F_in    = (const float*)d_in[0];
    const float* theta   = (const float*)d_in[1];
    const float* W_bias  = (const float*)d_in[2];
    const float* W_cos   = (const float*)d_in[3];
    const float* W_sin   = (const float*)d_in[4];
    const float* Wb_bias = (const float*)d_in[5];
    const float* Wb_cos  = (const float*)d_in[6];
    const float* Wb_sin  = (const float*)d_in[7];
    float* out = (float*)d_out;

    // out is re-poisoned before every timed launch; atomics need zeros.
    hipMemsetAsync(out, 0, (size_t)out_size * sizeof(float), stream);

    dim3 grid(NRO_CL, NRO_B / 256, 2);   // (j, b-group, i-split) = 64*2*2 = 256 blocks
    nro_main_kernel<<<grid, 256, 0, stream>>>(
        F_in, theta, W_bias, W_cos, W_sin, Wb_bias, Wb_cos, Wb_sin, out);
}